// Round 9
// baseline (107.003 us; speedup 1.0000x reference)
//
#include <hip/hip_runtime.h>
#include <hip/hip_bf16.h>
#include <stdint.h>

// ComplexDFT256: out(65536x512) = X(65536x512) @ W^T, W = [[cos,-sin],[sin,cos]].
// Transposed MFMA (D[j][b]). X staged fp32 via global_load_lds (width 16) into a
// TRIPLE-buffered LDS tile, prefetch distance 2 -> no wait in the K-loop ever
// blocks on a load younger than ~2 iterations. Swizzle: linear LDS dest +
// inverse-permuted global source + XOR on read (rule #21).

typedef __attribute__((ext_vector_type(8))) short bf16x8;
typedef __attribute__((ext_vector_type(4))) float f32x4;

#define KDIM 512
#define NDIM 512
#define BM 64

__device__ __forceinline__ ushort f2bf(float f) {
  union { float f; uint32_t u; } v; v.f = f;
  uint32_t r = (v.u + 0x7fffu + ((v.u >> 16) & 1u)) >> 16;  // RNE
  return (ushort)r;
}

// Fragment-ordered W: Wf[8*g .. 8*g+7], g = k5*2048 + nt*64 + lane, holds
// W[j = nt*16 + (lane&15)][k = k5*32 + (lane>>4)*8 + e]  (e = 0..7)
__global__ __launch_bounds__(512) void build_w_kernel(const float* __restrict__ cosk,
                                                      const float* __restrict__ sink,
                                                      ushort* __restrict__ Wf) {
  int g = blockIdx.x * 512 + threadIdx.x;   // 0..32767
  int lane = g & 63;
  int nt = (g >> 6) & 31;
  int j = nt * 16 + (lane & 15);
  int kbase = (g >> 11) * 32 + (lane >> 4) * 8;
  bf16x8 w8;
#pragma unroll
  for (int e = 0; e < 8; ++e) {
    int k = kbase + e;
    float v;
    if (j < 256) {
      v = (k < 256) ? cosk[(j << 8) + k] : -sink[(j << 8) + (k - 256)];
    } else {
      int jj = j - 256;
      v = (k < 256) ? sink[(jj << 8) + k] : cosk[(jj << 8) + (k - 256)];
    }
    w8[e] = (short)f2bf(v);
  }
  *reinterpret_cast<bf16x8*>(Wf + (size_t)g * 8) = w8;
}

__device__ __forceinline__ void gload_lds16(const float* g, float* l) {
  __builtin_amdgcn_global_load_lds(
      (__attribute__((address_space(1))) const void*)g,
      (__attribute__((address_space(3))) void*)l, 16, 0, 0);
}

__device__ __forceinline__ bf16x8 cvt8(f32x4 a, f32x4 b) {
  bf16x8 w8;
  w8[0] = (short)f2bf(a[0]); w8[1] = (short)f2bf(a[1]);
  w8[2] = (short)f2bf(a[2]); w8[3] = (short)f2bf(a[3]);
  w8[4] = (short)f2bf(b[0]); w8[5] = (short)f2bf(b[1]);
  w8[6] = (short)f2bf(b[2]); w8[7] = (short)f2bf(b[3]);
  return w8;
}

// Block = 64 batch rows x full 512 j, 8 waves (each 64 j x 64 batch).
// LDS: 3 x (64 rows x 64 k) fp32 tiles = 48 KB.
// Per tile, wave w DMAs rows [w*8, w*8+8) as two 1KB global_load_lds.
__global__ __launch_bounds__(512) void dft_gemm_kernel(const float* __restrict__ A,
                                                       const ushort* __restrict__ Wf,
                                                       float* __restrict__ out) {
  __shared__ float Xs[3][BM * 64];   // 48 KB

  const int tid  = threadIdx.x;
  const int lane = tid & 63;
  const int wid  = tid >> 6;            // 0..7
  const int m0   = blockIdx.x * BM;
  const int c0   = wid * 64;            // j base for this wave

  // ---- staging addresses ----
  // DMA writes LDS linearly: lane l of chunk (wid,q) -> fp32 [wid*512+q*256+l*4, +4)
  //   = row (wid*8 + q*4 + l/16), cols (l&15)*4 .. +3.
  // We want LDS[row][c] = X[row][(slot(c) ^ (row&7))*8 + c%8]  (slot = c/8),
  // so the global source for lane l is col ((slin ^ (row&7))<<3) + (l&1)*4.
  const int r0 = wid * 8 + (lane >> 4);     // q=0 row
  const int r1 = r0 + 4;                    // q=1 row
  const int slin = (lane & 15) >> 1;
  const int h4   = (lane & 1) << 2;
  const float* g0 = A + (size_t)(m0 + r0) * KDIM + (((slin ^ (r0 & 7)) << 3) + h4);
  const float* g1 = A + (size_t)(m0 + r1) * KDIM + (((slin ^ (r1 & 7)) << 3) + h4);

  const int lrow = lane & 15;
  const int g16  = lane >> 4;          // 0..3

  // W frag base: ((t*2+kk)*32 + nt)*512 + lane*8; nt = c0/16 + mi
  const ushort* wp = Wf + (size_t)(c0 >> 4) * 512 + lane * 8;

  f32x4 acc[4][4] = {};   // [mi = j-tile][ni = batch-tile]

  // ---- prologue: DMA tiles 0 and 1 ----
  gload_lds16(g0,      &Xs[0][wid * 512]);
  gload_lds16(g1,      &Xs[0][wid * 512 + 256]);
  gload_lds16(g0 + 64, &Xs[1][wid * 512]);
  gload_lds16(g1 + 64, &Xs[1][wid * 512 + 256]);
  asm volatile("s_waitcnt vmcnt(2)" ::: "memory");   // tile 0 landed
  __builtin_amdgcn_sched_barrier(0);
  __builtin_amdgcn_s_barrier();

#pragma unroll
  for (int t = 0; t < 8; ++t) {
    // 1) W loads for step t (coalesced 1KB L2 streams; compiler emits counted
    //    vmcnt waits that also force the iteration-old stag(t+1) to completion)
    bf16x8 wfr[2][4];
#pragma unroll
    for (int kk = 0; kk < 2; ++kk)
#pragma unroll
      for (int mi = 0; mi < 4; ++mi)
        wfr[kk][mi] = *reinterpret_cast<const bf16x8*>(
            wp + (size_t)((t * 2 + kk) * 32 + mi) * 512);

    // 2) DMA tile t+2 (distance 2: ~2 iterations to complete)
    if (t < 6) {
      gload_lds16(g0 + (t + 2) * 64, &Xs[(t + 2) % 3][wid * 512]);
      gload_lds16(g1 + (t + 2) * 64, &Xs[(t + 2) % 3][wid * 512 + 256]);
    }

    // 3) LDS reads (fp32, XOR-deswizzled) + cvt + MFMAs
#pragma unroll
    for (int kk = 0; kk < 2; ++kk) {
      bf16x8 xfr[4];
#pragma unroll
      for (int ni = 0; ni < 4; ++ni) {
        int row = ni * 16 + lrow;
        int s = kk * 4 + g16;
        const float* p = &Xs[t % 3][(row << 6) + ((s ^ (row & 7)) << 3)];
        f32x4 a = *reinterpret_cast<const f32x4*>(p);
        f32x4 b = *reinterpret_cast<const f32x4*>(p + 4);
        xfr[ni] = cvt8(a, b);
      }
#pragma unroll
      for (int mi = 0; mi < 4; ++mi)
#pragma unroll
        for (int ni = 0; ni < 4; ++ni)
          acc[mi][ni] = __builtin_amdgcn_mfma_f32_16x16x32_bf16(
              wfr[kk][mi], xfr[ni], acc[mi][ni], 0, 0, 0);
    }

    // 4) barrier only (no vmem drain: stag(t+1) already forced complete by the
    //    W-waits above; stag(t+2) stays in flight across the barrier)
    if (t < 7) {
      __builtin_amdgcn_sched_barrier(0);
      __builtin_amdgcn_s_barrier();
    }
  }

  // ---- epilogue: lane holds 4 contiguous j's -> f32x4 stores ----
  const int jbase = c0 + (lane >> 4) * 4;
#pragma unroll
  for (int ni = 0; ni < 4; ++ni) {
    size_t rowb = (size_t)(m0 + ni * 16 + lrow) * NDIM;
#pragma unroll
    for (int mi = 0; mi < 4; ++mi)
      *reinterpret_cast<f32x4*>(out + rowb + jbase + mi * 16) = acc[mi][ni];
  }
}

extern "C" void kernel_launch(void* const* d_in, const int* in_sizes, int n_in,
                              void* d_out, int out_size, void* d_ws, size_t ws_size,
                              hipStream_t stream) {
  const float* x    = (const float*)d_in[0];   // (65536, 2, 256) fp32
  const float* cosk = (const float*)d_in[1];   // (256, 256) fp32
  const float* sink = (const float*)d_in[2];   // (256, 256) fp32
  float* out = (float*)d_out;                  // (65536, 512, 1) fp32
  ushort* Wf = (ushort*)d_ws;                  // 512 KB fragment-ordered W

  build_w_kernel<<<64, 512, 0, stream>>>(cosk, sink, Wf);
  dft_gemm_kernel<<<65536 / BM, 512, 0, stream>>>(x, Wf, out);
}

// Round 10
// 87.198 us; speedup vs baseline: 1.2271x; 1.2271x over previous
//
#include <hip/hip_runtime.h>
#include <hip/hip_bf16.h>
#include <stdint.h>

// ComplexDFT256: out(65536x512) = X(65536x512) @ W^T, W = [[cos,-sin],[sin,cos]].
// R5 K-loop (best: 88us) + LDS-transposed epilogue: stores become contiguous
// 512B-per-instruction sequential row streams instead of 16x64B scatters.

typedef __attribute__((ext_vector_type(8))) short bf16x8;
typedef __attribute__((ext_vector_type(4))) float f32x4;
typedef __attribute__((ext_vector_type(2))) float f32x2;

#define KDIM 512
#define NDIM 512
#define BM 64

__device__ __forceinline__ ushort f2bf(float f) {
  union { float f; uint32_t u; } v; v.f = f;
  uint32_t r = (v.u + 0x7fffu + ((v.u >> 16) & 1u)) >> 16;  // RNE
  return (ushort)r;
}

// Fragment-ordered W: Wf[8*g .. 8*g+7], g = k5*2048 + nt*64 + lane, holds
// W[j = nt*16 + (lane&15)][k = k5*32 + (lane>>4)*8 + e]  (e = 0..7)
__global__ __launch_bounds__(512) void build_w_kernel(const float* __restrict__ cosk,
                                                      const float* __restrict__ sink,
                                                      ushort* __restrict__ Wf) {
  int g = blockIdx.x * 512 + threadIdx.x;   // 0..32767
  int lane = g & 63;
  int nt = (g >> 6) & 31;
  int j = nt * 16 + (lane & 15);
  int kbase = (g >> 11) * 32 + (lane >> 4) * 8;
  bf16x8 w8;
#pragma unroll
  for (int e = 0; e < 8; ++e) {
    int k = kbase + e;
    float v;
    if (j < 256) {
      v = (k < 256) ? cosk[(j << 8) + k] : -sink[(j << 8) + (k - 256)];
    } else {
      int jj = j - 256;
      v = (k < 256) ? sink[(jj << 8) + k] : cosk[(jj << 8) + (k - 256)];
    }
    w8[e] = (short)f2bf(v);
  }
  *reinterpret_cast<bf16x8*>(Wf + (size_t)g * 8) = w8;
}

__device__ __forceinline__ bf16x8 cvt8(f32x4 a, f32x4 b) {
  bf16x8 w8;
  w8[0] = (short)f2bf(a[0]); w8[1] = (short)f2bf(a[1]);
  w8[2] = (short)f2bf(a[2]); w8[3] = (short)f2bf(a[3]);
  w8[4] = (short)f2bf(b[0]); w8[5] = (short)f2bf(b[1]);
  w8[6] = (short)f2bf(b[2]); w8[7] = (short)f2bf(b[3]);
  return w8;
}

// Block = 64 batch rows x full 512 output cols, 8 waves (each 64 j x 64 b).
// X staged in double-buffered LDS (bf16, XOR-swizzled); W frags streamed from L2.
__global__ __launch_bounds__(512) void dft_gemm_kernel(const float* __restrict__ A,
                                                       const ushort* __restrict__ Wf,
                                                       float* __restrict__ out) {
  __shared__ ushort As[2][BM * 64];   // 16 KB
  __shared__ float  Cs[64][130];      // 33.3 KB, pad=2 -> conflict-free transpose

  const int tid  = threadIdx.x;
  const int lane = tid & 63;
  const int wid  = tid >> 6;            // 0..7
  const int m0   = blockIdx.x * BM;     // batch-row base
  const int c0   = wid * 64;            // j base for this wave

  // staging: 512 threads, each 8 floats (two f32x4) of one row per K-tile
  const int srow = tid >> 3;
  const int skq  = (tid & 7) * 8;
  const float* ap = A + (size_t)(m0 + srow) * KDIM + skq;
  const int swidx = (srow << 6) + (skq ^ ((srow & 7) << 3));

  const int lrow = lane & 15;
  const int lk8  = (lane >> 4) * 8;

  // W frag base: (k5*32 + nt)*512 + lane*8 elems; nt = c0/16 + mi, k5 = t*2 + kk
  const ushort* wp = Wf + (size_t)(c0 >> 4) * 512 + lane * 8;

  f32x4 acc[4][4] = {};   // acc[mi][ni]: mi = j-tile, ni = b-tile

  // ---- prologue: tile 0 -> LDS[0], tile 1 in flight ----
  f32x4 q0 = *reinterpret_cast<const f32x4*>(ap);
  f32x4 q1 = *reinterpret_cast<const f32x4*>(ap + 4);
  f32x4 p0 = *reinterpret_cast<const f32x4*>(ap + 64);
  f32x4 p1 = *reinterpret_cast<const f32x4*>(ap + 68);
  *reinterpret_cast<bf16x8*>(&As[0][swidx]) = cvt8(q0, q1);
  asm volatile("s_waitcnt lgkmcnt(0)" ::: "memory");
  __builtin_amdgcn_s_barrier();

#pragma unroll
  for (int t = 0; t < 8; ++t) {
    // 1) write next X tile to the other buffer (waits on p via auto vmcnt)
    if (t < 7)
      *reinterpret_cast<bf16x8*>(&As[(t + 1) & 1][swidx]) = cvt8(p0, p1);

    // 2) issue all 8 W frag loads for this K-step (coalesced 1KB streams from L2)
    bf16x8 wfr[2][4];
#pragma unroll
    for (int kk = 0; kk < 2; ++kk)
#pragma unroll
      for (int mi = 0; mi < 4; ++mi)
        wfr[kk][mi] = *reinterpret_cast<const bf16x8*>(
            wp + (size_t)((t * 2 + kk) * 32 + mi) * 512);

    // 3) issue X tile t+2 (lands ~1 full iteration later)
    if (t < 6) {
      p0 = *reinterpret_cast<const f32x4*>(ap + (t + 2) * 64);
      p1 = *reinterpret_cast<const f32x4*>(ap + (t + 2) * 64 + 4);
    }

    // 4) LDS reads + MFMAs
#pragma unroll
    for (int kk = 0; kk < 2; ++kk) {
      bf16x8 xfr[4];
#pragma unroll
      for (int ni = 0; ni < 4; ++ni) {
        int row = ni * 16 + lrow;
        int idx = (row << 6) + ((kk * 32 + lk8) ^ ((lrow & 7) << 3));
        xfr[ni] = *reinterpret_cast<const bf16x8*>(&As[t & 1][idx]);
      }
#pragma unroll
      for (int mi = 0; mi < 4; ++mi)
#pragma unroll
        for (int ni = 0; ni < 4; ++ni)
          acc[mi][ni] = __builtin_amdgcn_mfma_f32_16x16x32_bf16(
              wfr[kk][mi], xfr[ni], acc[mi][ni], 0, 0, 0);
    }

    // 5) single barrier per K-step; only LDS drained (vmem stays in flight)
    if (t < 7) {
      asm volatile("s_waitcnt lgkmcnt(0)" ::: "memory");
      __builtin_amdgcn_s_barrier();
    }
  }

  // ---- epilogue: 4 x 128-j chunks through LDS transpose ----
  // Cs[b][jj] = out value at (m0+b, c*128+jj). Owning waves (wid>>1 == c)
  // ds_write acc; then all 8 waves store rows as contiguous 512B runs.
  const int cown   = wid >> 1;
  const int joff_w = ((wid & 1) << 6) + ((lane >> 4) << 2);
#pragma unroll
  for (int c = 0; c < 4; ++c) {
    if (cown == c) {
#pragma unroll
      for (int ni = 0; ni < 4; ++ni) {
        int b = ni * 16 + lrow;
#pragma unroll
        for (int mi = 0; mi < 4; ++mi)
          *reinterpret_cast<f32x4*>(&Cs[b][joff_w + mi * 16]) = acc[mi][ni];
      }
    }
    asm volatile("s_waitcnt lgkmcnt(0)" ::: "memory");
    __builtin_amdgcn_s_barrier();

#pragma unroll
    for (int r = 0; r < 8; ++r) {
      int b = wid * 8 + r;
      f32x2 v = *reinterpret_cast<const f32x2*>(&Cs[b][lane * 2]);
      *reinterpret_cast<f32x2*>(out + (size_t)(m0 + b) * NDIM + c * 128 + lane * 2) = v;
    }
    if (c < 3) {
      asm volatile("s_waitcnt lgkmcnt(0)" ::: "memory");
      __builtin_amdgcn_s_barrier();
    }
  }
}

extern "C" void kernel_launch(void* const* d_in, const int* in_sizes, int n_in,
                              void* d_out, int out_size, void* d_ws, size_t ws_size,
                              hipStream_t stream) {
  const float* x    = (const float*)d_in[0];   // (65536, 2, 256) fp32
  const float* cosk = (const float*)d_in[1];   // (256, 256) fp32
  const float* sink = (const float*)d_in[2];   // (256, 256) fp32
  float* out = (float*)d_out;                  // (65536, 512, 1) fp32
  ushort* Wf = (ushort*)d_ws;                  // 512 KB fragment-ordered W

  build_w_kernel<<<64, 512, 0, stream>>>(cosk, sink, Wf);
  dft_gemm_kernel<<<65536 / BM, 512, 0, stream>>>(x, Wf, out);
}